// Round 1
// baseline (269.115 us; speedup 1.0000x reference)
//
#include <hip/hip_runtime.h>
#include <hip/hip_bf16.h>
#include <math.h>

#define TT 8192
#define DD 512
#define HH 1024
#define EE 16
#define NSLOT 18432   // 144 * 128 max padded slots
#define MAXTILES 144
#define BM 128

typedef __attribute__((ext_vector_type(8))) short bf16x8;
typedef __attribute__((ext_vector_type(4))) float f32x4;

__device__ __forceinline__ unsigned short f2bf(float f) {
  union { float f; unsigned u; } v; v.f = f;
  unsigned r = v.u + 0x7fffu + ((v.u >> 16) & 1u);
  return (unsigned short)(r >> 16);
}

__device__ __forceinline__ void gload16(const void* g, void* l) {
  __builtin_amdgcn_global_load_lds(
      (const __attribute__((address_space(1))) unsigned int*)g,
      (__attribute__((address_space(3))) unsigned int*)l, 16, 0, 0);
}

// ---------------- convert x f32 -> bf16 ----------------
__global__ __launch_bounds__(256) void convert_x_kernel(
    const float* __restrict__ in, unsigned short* __restrict__ out, int n8) {
  int i = blockIdx.x * blockDim.x + threadIdx.x;
  if (i >= n8) return;
  const float4* p = (const float4*)in + (size_t)i * 2;
  float4 a = p[0], b = p[1];
  ushort4 lo, hi;
  lo.x = f2bf(a.x); lo.y = f2bf(a.y); lo.z = f2bf(a.z); lo.w = f2bf(a.w);
  hi.x = f2bf(b.x); hi.y = f2bf(b.y); hi.z = f2bf(b.z); hi.w = f2bf(b.w);
  ushort4* o = (ushort4*)out;
  o[(size_t)i * 2] = lo;
  o[(size_t)i * 2 + 1] = hi;
}

// ------- transpose+convert: in f32 [nmat][R][C] -> out bf16 [nmat][C][R] -------
__global__ __launch_bounds__(256) void transpose_cv_kernel(
    const float* __restrict__ in, unsigned short* __restrict__ out, int R, int C) {
  int mat = blockIdx.z;
  int c0 = blockIdx.x * 64;
  int r0 = blockIdx.y * 64;
  const float* src = in + (size_t)mat * R * C;
  unsigned short* dst = out + (size_t)mat * R * C;
  __shared__ unsigned short t[64][68];
  int tid = threadIdx.x;
#pragma unroll
  for (int p = 0; p < 4; p++) {
    int r = tid >> 2;
    int c4 = (tid & 3) + p * 4;
    float4 v = *(const float4*)(src + (size_t)(r0 + r) * C + c0 + c4 * 4);
    t[c4 * 4 + 0][r] = f2bf(v.x);
    t[c4 * 4 + 1][r] = f2bf(v.y);
    t[c4 * 4 + 2][r] = f2bf(v.z);
    t[c4 * 4 + 3][r] = f2bf(v.w);
  }
  __syncthreads();
#pragma unroll
  for (int p = 0; p < 4; p++) {
    int oc = (tid >> 4) + p * 16;
    int ch = tid & 15;
    ushort4 v = *(ushort4*)(&t[oc][ch * 4]);
    *(ushort4*)(dst + (size_t)(c0 + oc) * R + r0 + ch * 4) = v;
  }
}

// ---------------- gate: logits -> top2 -> softmax -> counts ----------------
__global__ __launch_bounds__(256) void gate_kernel(
    const float* __restrict__ x, const float* __restrict__ Wg,
    const float* __restrict__ bg, int* __restrict__ gate_e,
    float* __restrict__ gate_w, int* __restrict__ counts) {
  int tid = threadIdx.x;
  int tt = tid >> 4, e = tid & 15;
  int tok = blockIdx.x * 16 + tt;
  const float4* xr = (const float4*)(x + (size_t)tok * DD);
  double acc = 0.0;
#pragma unroll 8
  for (int i = 0; i < DD / 4; i++) {
    float4 v = xr[i];
    int d = i * 4;
    acc += (double)v.x * (double)Wg[(d + 0) * EE + e];
    acc += (double)v.y * (double)Wg[(d + 1) * EE + e];
    acc += (double)v.z * (double)Wg[(d + 2) * EE + e];
    acc += (double)v.w * (double)Wg[(d + 3) * EE + e];
  }
  float logit = (float)(acc + (double)bg[e]);
  __shared__ float lg[16][17];
  lg[tt][e] = logit;
  __syncthreads();
  if (tid < 16) {
    int t2 = tid;
    float v1 = -1e30f, v2 = -1e30f;
    int i1 = 0, i2 = 0;
#pragma unroll
    for (int q = 0; q < EE; q++) {
      float v = lg[t2][q];
      if (v > v1) { v2 = v1; i2 = i1; v1 = v; i1 = q; }
      else if (v > v2) { v2 = v; i2 = q; }
    }
    float p = expf(v2 - v1);
    float s = 1.0f / (1.0f + p);
    int gtok = blockIdx.x * 16 + t2;
    gate_e[gtok * 2] = i1;
    gate_e[gtok * 2 + 1] = i2;
    gate_w[gtok * 2] = s;
    gate_w[gtok * 2 + 1] = p * s;
    atomicAdd(&counts[i1], 1);
    atomicAdd(&counts[i2], 1);
  }
}

// ---------------- scan: padded offsets + tile->expert map ----------------
__global__ void scan_kernel(const int* __restrict__ counts, int* __restrict__ offs,
                            int* __restrict__ tile_expert, int* __restrict__ ntiles,
                            int* __restrict__ fill) {
  if (threadIdx.x == 0 && blockIdx.x == 0) {
    int off = 0, nt = 0;
    for (int e = 0; e < EE; e++) {
      offs[e] = off;
      fill[e] = 0;
      int tiles = (counts[e] + BM - 1) / BM;
      for (int t = 0; t < tiles; t++) tile_expert[nt++] = e;
      off += tiles * BM;
    }
    offs[EE] = off;
    ntiles[0] = nt;
  }
}

// ---------------- scatter tokens to slots ----------------
__global__ __launch_bounds__(256) void scatter_kernel(
    const int* __restrict__ gate_e, const float* __restrict__ gate_w,
    const int* __restrict__ offs, int* __restrict__ fill,
    int* __restrict__ slot_token, float* __restrict__ slot_w) {
  int t = blockIdx.x * blockDim.x + threadIdx.x;
  if (t >= TT) return;
#pragma unroll
  for (int k = 0; k < 2; k++) {
    int e = gate_e[t * 2 + k];
    int pos = atomicAdd(&fill[e], 1);
    int slot = offs[e] + pos;
    slot_token[slot] = t;
    slot_w[slot] = gate_w[t * 2 + k];
  }
}

// ---------------- GEMM1: h = gelu(x[slot] @ W1[e] + b1[e]) ----------------
// A: gathered xb rows [slot][DD] bf16; B: w1t[e] = W1^T [HH][DD] bf16
__global__ __launch_bounds__(256) void gemm1_kernel(
    const unsigned short* __restrict__ xb, const unsigned short* __restrict__ w1t,
    const float* __restrict__ b1, const int* __restrict__ slot_token,
    const int* __restrict__ tile_expert, const int* __restrict__ ntiles,
    unsigned short* __restrict__ hb) {
  int mt = blockIdx.x;
  if (mt >= ntiles[0]) return;
  int e = tile_expert[mt];
  int row0 = mt * BM;
  int n0 = blockIdx.y * 128;
  __shared__ unsigned short As[128][32];
  __shared__ unsigned short Bs[128][32];
  int tid = threadIdx.x;
  int lane = tid & 63;
  int wave = tid >> 6;
  int wm = wave >> 1, wn = wave & 1;
  int ra = tid >> 2, c = tid & 3;
  int tok_a = slot_token[row0 + ra]; if (tok_a < 0) tok_a = 0;
  int tok_b = slot_token[row0 + ra + 64]; if (tok_b < 0) tok_b = 0;
  const unsigned short* wbase = w1t + ((size_t)e * HH * DD);
  f32x4 acc[4][4];
#pragma unroll
  for (int m = 0; m < 4; m++)
#pragma unroll
    for (int n = 0; n < 4; n++) {
      f32x4 z = {0.f, 0.f, 0.f, 0.f};
      acc[m][n] = z;
    }
  for (int kk = 0; kk < DD / 32; kk++) {
    int k0 = kk * 32;
    __syncthreads();
    gload16(xb + (size_t)tok_a * DD + k0 + c * 8, &As[ra][c * 8]);
    gload16(xb + (size_t)tok_b * DD + k0 + c * 8, &As[ra + 64][c * 8]);
    gload16(wbase + (size_t)(n0 + ra) * DD + k0 + c * 8, &Bs[ra][c * 8]);
    gload16(wbase + (size_t)(n0 + ra + 64) * DD + k0 + c * 8, &Bs[ra + 64][c * 8]);
    __syncthreads();
    bf16x8 a[4], b[4];
#pragma unroll
    for (int m = 0; m < 4; m++)
      a[m] = *(const bf16x8*)(&As[wm * 64 + m * 16 + (lane & 15)][(lane >> 4) * 8]);
#pragma unroll
    for (int n = 0; n < 4; n++)
      b[n] = *(const bf16x8*)(&Bs[wn * 64 + n * 16 + (lane & 15)][(lane >> 4) * 8]);
#pragma unroll
    for (int m = 0; m < 4; m++)
#pragma unroll
      for (int n = 0; n < 4; n++)
        acc[m][n] = __builtin_amdgcn_mfma_f32_16x16x32_bf16(a[m], b[n], acc[m][n], 0, 0, 0);
  }
  const float* b1e = b1 + (size_t)e * HH;
#pragma unroll
  for (int m = 0; m < 4; m++) {
#pragma unroll
    for (int r = 0; r < 4; r++) {
      int slot = row0 + wm * 64 + m * 16 + ((lane >> 4) << 2) + r;
      unsigned short* hrow = hb + (size_t)slot * HH;
#pragma unroll
      for (int n = 0; n < 4; n++) {
        int hc = n0 + wn * 64 + n * 16 + (lane & 15);
        float v = acc[m][n][r] + b1e[hc];
        v = 0.5f * v * (1.0f + erff(v * 0.70710678118654752f));
        hrow[hc] = f2bf(v);
      }
    }
  }
}

// ---------------- GEMM2: out[tok] += w * (h[slot] @ W2[e] + b2[e]) ----------------
// A: hb rows [slot][HH] bf16; B: w2t[e] = W2^T [DD][HH] bf16
__global__ __launch_bounds__(256) void gemm2_kernel(
    const unsigned short* __restrict__ hb, const unsigned short* __restrict__ w2t,
    const float* __restrict__ b2, const int* __restrict__ slot_token,
    const float* __restrict__ slot_w, const int* __restrict__ tile_expert,
    const int* __restrict__ ntiles, float* __restrict__ out) {
  int mt = blockIdx.x;
  if (mt >= ntiles[0]) return;
  int e = tile_expert[mt];
  int row0 = mt * BM;
  int n0 = blockIdx.y * 128;
  __shared__ unsigned short As[128][32];
  __shared__ unsigned short Bs[128][32];
  int tid = threadIdx.x;
  int lane = tid & 63;
  int wave = tid >> 6;
  int wm = wave >> 1, wn = wave & 1;
  int ra = tid >> 2, c = tid & 3;
  const unsigned short* wbase = w2t + ((size_t)e * DD * HH);
  f32x4 acc[4][4];
#pragma unroll
  for (int m = 0; m < 4; m++)
#pragma unroll
    for (int n = 0; n < 4; n++) {
      f32x4 z = {0.f, 0.f, 0.f, 0.f};
      acc[m][n] = z;
    }
  for (int kk = 0; kk < HH / 32; kk++) {
    int k0 = kk * 32;
    __syncthreads();
    gload16(hb + (size_t)(row0 + ra) * HH + k0 + c * 8, &As[ra][c * 8]);
    gload16(hb + (size_t)(row0 + ra + 64) * HH + k0 + c * 8, &As[ra + 64][c * 8]);
    gload16(wbase + (size_t)(n0 + ra) * HH + k0 + c * 8, &Bs[ra][c * 8]);
    gload16(wbase + (size_t)(n0 + ra + 64) * HH + k0 + c * 8, &Bs[ra + 64][c * 8]);
    __syncthreads();
    bf16x8 a[4], b[4];
#pragma unroll
    for (int m = 0; m < 4; m++)
      a[m] = *(const bf16x8*)(&As[wm * 64 + m * 16 + (lane & 15)][(lane >> 4) * 8]);
#pragma unroll
    for (int n = 0; n < 4; n++)
      b[n] = *(const bf16x8*)(&Bs[wn * 64 + n * 16 + (lane & 15)][(lane >> 4) * 8]);
#pragma unroll
    for (int m = 0; m < 4; m++)
#pragma unroll
      for (int n = 0; n < 4; n++)
        acc[m][n] = __builtin_amdgcn_mfma_f32_16x16x32_bf16(a[m], b[n], acc[m][n], 0, 0, 0);
  }
  const float* b2e = b2 + (size_t)e * DD;
#pragma unroll
  for (int m = 0; m < 4; m++) {
#pragma unroll
    for (int r = 0; r < 4; r++) {
      int slot = row0 + wm * 64 + m * 16 + ((lane >> 4) << 2) + r;
      int tok = slot_token[slot];
      if (tok >= 0) {
        float w = slot_w[slot];
        float* orow = out + (size_t)tok * DD;
#pragma unroll
        for (int n = 0; n < 4; n++) {
          int dc = n0 + wn * 64 + n * 16 + (lane & 15);
          float v = acc[m][n][r] + b2e[dc];
          atomicAdd(&orow[dc], w * v);
        }
      }
    }
  }
}

extern "C" void kernel_launch(void* const* d_in, const int* in_sizes, int n_in,
                              void* d_out, int out_size, void* d_ws, size_t ws_size,
                              hipStream_t stream) {
  const float* x  = (const float*)d_in[0];
  const float* Wg = (const float*)d_in[1];
  const float* bg = (const float*)d_in[2];
  const float* W1 = (const float*)d_in[3];
  const float* b1 = (const float*)d_in[4];
  const float* W2 = (const float*)d_in[5];
  const float* b2 = (const float*)d_in[6];
  float* out = (float*)d_out;

  uint8_t* w = (uint8_t*)d_ws;
  size_t o = 0;
  unsigned short* xb  = (unsigned short*)(w + o); o += (size_t)TT * DD * 2;       // 8 MB
  unsigned short* w1t = (unsigned short*)(w + o); o += (size_t)EE * DD * HH * 2;  // 16 MB
  unsigned short* w2t = (unsigned short*)(w + o); o += (size_t)EE * DD * HH * 2;  // 16 MB
  unsigned short* hb  = (unsigned short*)(w + o); o += (size_t)NSLOT * HH * 2;    // 36 MB
  int*   slot_token = (int*)(w + o);   o += (size_t)NSLOT * 4;
  float* slot_w     = (float*)(w + o); o += (size_t)NSLOT * 4;
  int*   gate_e     = (int*)(w + o);   o += (size_t)TT * 2 * 4;
  float* gate_w     = (float*)(w + o); o += (size_t)TT * 2 * 4;
  int*   counts     = (int*)(w + o);   o += 64;
  int*   fill       = (int*)(w + o);   o += 64;
  int*   offs       = (int*)(w + o);   o += 128;
  int*   tile_expert= (int*)(w + o);   o += 640;
  int*   ntiles     = (int*)(w + o);   o += 64;

  hipMemsetAsync(counts, 0, 64, stream);
  hipMemsetAsync(slot_token, 0xFF, (size_t)NSLOT * 4, stream);
  hipMemsetAsync(d_out, 0, (size_t)TT * DD * 4, stream);

  // convert x -> bf16
  {
    int n8 = TT * DD / 8;
    convert_x_kernel<<<n8 / 256, 256, 0, stream>>>(x, xb, n8);
  }
  // W1 [E][D][H] -> w1t [E][H][D]
  {
    dim3 g(HH / 64, DD / 64, EE);
    transpose_cv_kernel<<<g, 256, 0, stream>>>(W1, w1t, DD, HH);
  }
  // W2 [E][H][D] -> w2t [E][D][H]
  {
    dim3 g(DD / 64, HH / 64, EE);
    transpose_cv_kernel<<<g, 256, 0, stream>>>(W2, w2t, HH, DD);
  }
  gate_kernel<<<TT / 16, 256, 0, stream>>>(x, Wg, bg, gate_e, gate_w, counts);
  scan_kernel<<<1, 64, 0, stream>>>(counts, offs, tile_expert, ntiles, fill);
  scatter_kernel<<<TT / 256, 256, 0, stream>>>(gate_e, gate_w, offs, fill, slot_token, slot_w);
  {
    dim3 g(MAXTILES, HH / 128);
    gemm1_kernel<<<g, 256, 0, stream>>>(xb, w1t, b1, slot_token, tile_expert, ntiles, hb);
  }
  {
    dim3 g(MAXTILES, DD / 128);
    gemm2_kernel<<<g, 256, 0, stream>>>(hb, w2t, b2, slot_token, slot_w, tile_expert, ntiles, out);
  }
}